// Round 3
// baseline (823.147 us; speedup 1.0000x reference)
//
#include <hip/hip_runtime.h>
#include <math.h>

#define N_NODES 50000
#define N_EDGES 800000
#define NFEAT 512
#define NHID 256
#define NCODE 64
#define NCLASS 40
#define NCLS_PAD 48

typedef __attribute__((ext_vector_type(8))) short short8;
typedef __attribute__((ext_vector_type(8))) unsigned short ushort8;
typedef __attribute__((ext_vector_type(4))) unsigned short ushort4v;
typedef __attribute__((ext_vector_type(4))) float floatx4;

__device__ inline unsigned short f2bf(float f) {
    unsigned u = __builtin_bit_cast(unsigned, f);
    u += 0x7fff + ((u >> 16) & 1);
    return (unsigned short)(u >> 16);
}

// ---------------- CSR build (by dst) ----------------
__global__ __launch_bounds__(256) void hist_kernel(const int* __restrict__ dst,
                                                   int* __restrict__ counts) {
    int t = blockIdx.x * 256 + threadIdx.x;
    if (t < N_EDGES) atomicAdd(&counts[dst[t]], 1);
}

__global__ __launch_bounds__(1024) void scan_kernel(const int* __restrict__ counts,
                                                    int* __restrict__ offsets) {
    __shared__ int sums[1024];
    int t = threadIdx.x;
    const int CH = (N_NODES + 1023) / 1024;  // 49
    int start = t * CH;
    int end = min(start + CH, N_NODES);
    int s = 0;
    for (int i = start; i < end; i++) s += counts[i];
    sums[t] = s;
    __syncthreads();
    for (int off = 1; off < 1024; off <<= 1) {
        int v = (t >= off) ? sums[t - off] : 0;
        __syncthreads();
        sums[t] += v;
        __syncthreads();
    }
    int run = (t == 0) ? 0 : sums[t - 1];
    for (int i = start; i < end; i++) {
        offsets[i] = run;
        run += counts[i];
    }
    if (t == 1023) offsets[N_NODES] = sums[1023];
}

__global__ __launch_bounds__(256) void scatter_kernel(const int* __restrict__ dst,
                                                      const int* __restrict__ src,
                                                      const float* __restrict__ w,
                                                      const int* __restrict__ offsets,
                                                      int* __restrict__ cursor,
                                                      int* __restrict__ src_s,
                                                      float* __restrict__ w_s) {
    int t = blockIdx.x * 256 + threadIdx.x;
    if (t < N_EDGES) {
        int d = dst[t];
        int pos = offsets[d] + atomicAdd(&cursor[d], 1);
        src_s[pos] = src[t];
        w_s[pos] = w[t];
    }
}

// ---------------- W1 transpose+cast: W1[512][256] f32 -> W1t[256][512] bf16 ----------------
__global__ __launch_bounds__(256) void w1t_kernel(const float* __restrict__ W1,
                                                  unsigned short* __restrict__ W1t) {
    int idx = blockIdx.x * 256 + threadIdx.x;
    if (idx < NFEAT * NHID) {
        int k = idx >> 8;
        int n = idx & 255;
        W1t[(size_t)n * NFEAT + k] = f2bf(W1[idx]);
    }
}

// ---------------- W2 transpose+cast+pad: W2[512][40] f32 -> W2bt[48][512] bf16 ----------------
__global__ __launch_bounds__(256) void w2t_kernel(const float* __restrict__ W2,
                                                  unsigned short* __restrict__ W2bt) {
    int idx = blockIdx.x * 256 + threadIdx.x;  // 48*512 = 24576
    if (idx < NCLS_PAD * NFEAT) {
        int n = idx >> 9;        // 0..47
        int k = idx & 511;
        W2bt[idx] = (n < NCLASS) ? f2bf(W2[(size_t)k * NCLASS + n]) : (unsigned short)0;
    }
}

// ---------------- GEMM1 (bf16 MFMA): support1 = x @ W1 ----------------
__global__ __launch_bounds__(256) void gemm1_mfma(const float* __restrict__ A,
                                                  const unsigned short* __restrict__ Bt,
                                                  float* __restrict__ C) {
    __shared__ unsigned short As[64][40];
    __shared__ unsigned short Bs[256][40];
    int t = threadIdx.x;
    int wave = t >> 6, lane = t & 63;
    int quad = lane >> 4, m16 = lane & 15;
    int m0 = blockIdx.x * 64;

    floatx4 acc[16];
#pragma unroll
    for (int i = 0; i < 16; i++) acc[i] = (floatx4){0.f, 0.f, 0.f, 0.f};

    int ar = t >> 2;
    int ako = (t & 3) * 8;
    int arow = m0 + ar;
    if (arow >= N_NODES) arow = N_NODES - 1;
    const float* Abase = A + (size_t)arow * NFEAT + ako;
    const unsigned short* Bbase = Bt + (size_t)t * NFEAT;

    for (int k0 = 0; k0 < NFEAT; k0 += 32) {
        float4 a0 = *(const float4*)(Abase + k0);
        float4 a1 = *(const float4*)(Abase + k0 + 4);
        ushort8 b0 = *(const ushort8*)(Bbase + k0);
        ushort8 b1 = *(const ushort8*)(Bbase + k0 + 8);
        ushort8 b2 = *(const ushort8*)(Bbase + k0 + 16);
        ushort8 b3 = *(const ushort8*)(Bbase + k0 + 24);
        __syncthreads();
        ushort8 av;
        av[0] = f2bf(a0.x); av[1] = f2bf(a0.y); av[2] = f2bf(a0.z); av[3] = f2bf(a0.w);
        av[4] = f2bf(a1.x); av[5] = f2bf(a1.y); av[6] = f2bf(a1.z); av[7] = f2bf(a1.w);
        *(ushort8*)&As[ar][ako] = av;
        *(ushort8*)&Bs[t][0]  = b0;
        *(ushort8*)&Bs[t][8]  = b1;
        *(ushort8*)&Bs[t][16] = b2;
        *(ushort8*)&Bs[t][24] = b3;
        __syncthreads();
        short8 afrag = *(const short8*)&As[wave * 16 + m16][quad * 8];
#pragma unroll
        for (int nt = 0; nt < 16; nt++) {
            short8 bfrag = *(const short8*)&Bs[nt * 16 + m16][quad * 8];
            acc[nt] = __builtin_amdgcn_mfma_f32_16x16x32_bf16(afrag, bfrag, acc[nt], 0, 0, 0);
        }
    }
#pragma unroll
    for (int nt = 0; nt < 16; nt++) {
#pragma unroll
        for (int r = 0; r < 4; r++) {
            int row = m0 + wave * 16 + quad * 4 + r;
            int col = nt * 16 + m16;
            if (row < N_NODES) C[(size_t)row * NHID + col] = acc[nt][r];
        }
    }
}

// ---------------- SpMM1 + bias + relu -> h1f (fp32) + x1cat[:,256:512] (bf16) ----------------
__global__ __launch_bounds__(256) void spmm1_kernel(const int* __restrict__ offsets,
                                                    const int* __restrict__ src_s,
                                                    const float* __restrict__ w_s,
                                                    const float* __restrict__ support1,
                                                    const float* __restrict__ b1,
                                                    float* __restrict__ h1f,
                                                    unsigned short* __restrict__ x1cat) {
    int n = blockIdx.x * 4 + (threadIdx.x >> 6);
    int lane = threadIdx.x & 63;
    int beg = offsets[n], end = offsets[n + 1];
    float ax = 0.f, ay = 0.f, az = 0.f, aw = 0.f;
    int i = beg;
    for (; i + 4 <= end; i += 4) {
        int s0 = src_s[i], s1 = src_s[i + 1], s2 = src_s[i + 2], s3 = src_s[i + 3];
        float w0 = w_s[i], w1 = w_s[i + 1], w2 = w_s[i + 2], w3 = w_s[i + 3];
        float4 r0 = *(const float4*)&support1[(size_t)s0 * NHID + lane * 4];
        float4 r1 = *(const float4*)&support1[(size_t)s1 * NHID + lane * 4];
        float4 r2 = *(const float4*)&support1[(size_t)s2 * NHID + lane * 4];
        float4 r3 = *(const float4*)&support1[(size_t)s3 * NHID + lane * 4];
        ax += w0 * r0.x + w1 * r1.x + w2 * r2.x + w3 * r3.x;
        ay += w0 * r0.y + w1 * r1.y + w2 * r2.y + w3 * r3.y;
        az += w0 * r0.z + w1 * r1.z + w2 * r2.z + w3 * r3.z;
        aw += w0 * r0.w + w1 * r1.w + w2 * r2.w + w3 * r3.w;
    }
    for (; i < end; i++) {
        int s = src_s[i];
        float ww = w_s[i];
        float4 r = *(const float4*)&support1[(size_t)s * NHID + lane * 4];
        ax += ww * r.x; ay += ww * r.y; az += ww * r.z; aw += ww * r.w;
    }
    float4 bb = *(const float4*)&b1[lane * 4];
    float4 h;
    h.x = fmaxf(ax + bb.x, 0.f);
    h.y = fmaxf(ay + bb.y, 0.f);
    h.z = fmaxf(az + bb.z, 0.f);
    h.w = fmaxf(aw + bb.w, 0.f);
    *(float4*)&h1f[(size_t)n * NHID + lane * 4] = h;
    ushort4v hb;
    hb[0] = f2bf(h.x); hb[1] = f2bf(h.y); hb[2] = f2bf(h.z); hb[3] = f2bf(h.w);
    *(ushort4v*)&x1cat[(size_t)n * (2 * NHID) + NHID + lane * 4] = hb;
}

// ---------------- Fused MLP: mu/lv -> z -> x1 (x1cat[:,0:256] bf16), 16 nodes/block ----------------
__global__ __launch_bounds__(256) void mlp_kernel(const float* __restrict__ h1f,
                                                  const float* __restrict__ eps,
                                                  const float* __restrict__ W_mu,
                                                  const float* __restrict__ b_mu,
                                                  const float* __restrict__ W_lv,
                                                  const float* __restrict__ b_lv,
                                                  const float* __restrict__ W_dec,
                                                  const float* __restrict__ b_dec,
                                                  unsigned short* __restrict__ x1cat) {
    __shared__ float smu[16][NCODE];  // 4 KB
    __shared__ float slv[16][NCODE];  // 4 KB
    __shared__ float sz[16][NCODE];   // 4 KB
    int t = threadIdx.x;
    int node0 = blockIdx.x * 16;
    // ---- phase A: mu/lv = h1 @ W_{mu,lv} + b ----
    {
        int j = t & 63;
        int which = (t >> 6) & 1;  // 0 = mu, 1 = lv (wave-uniform)
        int grp = t >> 7;          // node group (wave-uniform)
        const float* W = which ? W_lv : W_mu;
        float bias = which ? b_lv[j] : b_mu[j];
        float a[8];
#pragma unroll
        for (int n = 0; n < 8; n++) a[n] = bias;
        const float* hbase = h1f + (size_t)(node0 + grp * 8) * NHID;
        for (int k = 0; k < NHID; k += 4) {
            float w0 = W[(k + 0) * NCODE + j];
            float w1 = W[(k + 1) * NCODE + j];
            float w2 = W[(k + 2) * NCODE + j];
            float w3 = W[(k + 3) * NCODE + j];
#pragma unroll
            for (int n = 0; n < 8; n++) {
                float4 hv = *(const float4*)&hbase[n * NHID + k];  // wave-uniform -> s_load
                a[n] = fmaf(hv.x, w0, a[n]);
                a[n] = fmaf(hv.y, w1, a[n]);
                a[n] = fmaf(hv.z, w2, a[n]);
                a[n] = fmaf(hv.w, w3, a[n]);
            }
        }
        float* dstp = which ? &slv[grp * 8][0] : &smu[grp * 8][0];
#pragma unroll
        for (int n = 0; n < 8; n++) dstp[n * NCODE + j] = a[n];
    }
    __syncthreads();
    // ---- phase B: z = mu + eps*exp(lv) ----
#pragma unroll
    for (int r = 0; r < 4; r++) {
        int idx = t + r * 256;
        int n = idx >> 6, j = idx & 63;
        sz[n][j] = smu[n][j] + eps[(size_t)(node0 + n) * NCODE + j] * expf(slv[n][j]);
    }
    __syncthreads();
    // ---- phase C: x1 = relu(z @ W_dec + b_dec) ----
    {
        float acc[16];
        float bias = b_dec[t];
#pragma unroll
        for (int n = 0; n < 16; n++) acc[n] = bias;
        for (int k = 0; k < NCODE; k += 4) {
            float w0 = W_dec[(k + 0) * NHID + t];
            float w1 = W_dec[(k + 1) * NHID + t];
            float w2 = W_dec[(k + 2) * NHID + t];
            float w3 = W_dec[(k + 3) * NHID + t];
#pragma unroll
            for (int n = 0; n < 16; n++) {
                float4 zv = *(const float4*)&sz[n][k];  // ds_read_b128 broadcast
                acc[n] = fmaf(zv.x, w0, acc[n]);
                acc[n] = fmaf(zv.y, w1, acc[n]);
                acc[n] = fmaf(zv.z, w2, acc[n]);
                acc[n] = fmaf(zv.w, w3, acc[n]);
            }
        }
#pragma unroll
        for (int n = 0; n < 16; n++)
            x1cat[(size_t)(node0 + n) * 512 + t] = f2bf(fmaxf(acc[n], 0.f));
    }
}

// ---------------- GEMM2 (bf16 MFMA): support2 = x1cat @ W2  [50000,512]x[512,48->40] ----------------
__global__ __launch_bounds__(256) void gemm2_mfma(const unsigned short* __restrict__ Xb,
                                                  const unsigned short* __restrict__ Bt,
                                                  float* __restrict__ S2) {
    __shared__ unsigned short As[64][40];
    __shared__ unsigned short Bs[48][40];
    int t = threadIdx.x;
    int wave = t >> 6, lane = t & 63;
    int quad = lane >> 4, m16 = lane & 15;
    int m0 = blockIdx.x * 64;

    floatx4 acc[3];
#pragma unroll
    for (int i = 0; i < 3; i++) acc[i] = (floatx4){0.f, 0.f, 0.f, 0.f};

    int ar = t >> 2;
    int ako = (t & 3) * 8;
    int arow = m0 + ar;
    if (arow >= N_NODES) arow = N_NODES - 1;
    const unsigned short* Abase = Xb + (size_t)arow * NFEAT + ako;
    const unsigned short* Bbase = Bt + (size_t)(t >> 2) * NFEAT + ako;  // rows 0..63 (use 0..47)

    for (int k0 = 0; k0 < NFEAT; k0 += 32) {
        ushort8 a0 = *(const ushort8*)(Abase + k0);
        ushort8 b0;
        if ((t >> 2) < NCLS_PAD) b0 = *(const ushort8*)(Bbase + k0);
        __syncthreads();
        *(ushort8*)&As[ar][ako] = a0;
        if ((t >> 2) < NCLS_PAD) *(ushort8*)&Bs[t >> 2][ako] = b0;
        __syncthreads();
        short8 afrag = *(const short8*)&As[wave * 16 + m16][quad * 8];
#pragma unroll
        for (int nt = 0; nt < 3; nt++) {
            short8 bfrag = *(const short8*)&Bs[nt * 16 + m16][quad * 8];
            acc[nt] = __builtin_amdgcn_mfma_f32_16x16x32_bf16(afrag, bfrag, acc[nt], 0, 0, 0);
        }
    }
#pragma unroll
    for (int nt = 0; nt < 3; nt++) {
        int col = nt * 16 + m16;
        if (col < NCLASS) {
#pragma unroll
            for (int r = 0; r < 4; r++) {
                int row = m0 + wave * 16 + quad * 4 + r;
                if (row < N_NODES) S2[(size_t)row * NCLASS + col] = acc[nt][r];
            }
        }
    }
}

// ---------------- SpMM2 + bias + log_softmax -> out ----------------
__global__ __launch_bounds__(256) void spmm2_softmax_kernel(const int* __restrict__ offsets,
                                                            const int* __restrict__ src_s,
                                                            const float* __restrict__ w_s,
                                                            const float* __restrict__ S2,
                                                            const float* __restrict__ b2,
                                                            float* __restrict__ out) {
    int wave = threadIdx.x >> 6;
    int lane = threadIdx.x & 63;
    int n = blockIdx.x * 4 + wave;
    int beg = offsets[n], end = offsets[n + 1];
    float acc = 0.f;
    int i = beg;
    for (; i + 2 <= end; i += 2) {
        int s0 = src_s[i], s1 = src_s[i + 1];
        float w0 = w_s[i], w1 = w_s[i + 1];
        if (lane < NCLASS) {
            float v0 = S2[(size_t)s0 * NCLASS + lane];
            float v1 = S2[(size_t)s1 * NCLASS + lane];
            acc += w0 * v0 + w1 * v1;
        }
    }
    for (; i < end; i++) {
        int s = src_s[i];
        float ww = w_s[i];
        if (lane < NCLASS) acc += ww * S2[(size_t)s * NCLASS + lane];
    }
    float v = (lane < NCLASS) ? (acc + b2[lane]) : -INFINITY;
    float m = v;
#pragma unroll
    for (int off = 32; off > 0; off >>= 1) m = fmaxf(m, __shfl_xor(m, off));
    float ex = (lane < NCLASS) ? expf(v - m) : 0.f;
    float ssum = ex;
#pragma unroll
    for (int off = 32; off > 0; off >>= 1) ssum += __shfl_xor(ssum, off);
    if (lane < NCLASS) out[(size_t)n * NCLASS + lane] = v - m - logf(ssum);
}

extern "C" void kernel_launch(void* const* d_in, const int* in_sizes, int n_in,
                              void* d_out, int out_size, void* d_ws, size_t ws_size,
                              hipStream_t stream) {
    const float* x     = (const float*)d_in[0];
    const int*   esrc  = (const int*)d_in[1];
    const int*   edst  = (const int*)d_in[2];
    const float* ew    = (const float*)d_in[3];
    const float* eps   = (const float*)d_in[4];
    const float* W1    = (const float*)d_in[5];
    const float* b1    = (const float*)d_in[6];
    const float* W_mu  = (const float*)d_in[7];
    const float* b_mu  = (const float*)d_in[8];
    const float* W_lv  = (const float*)d_in[9];
    const float* b_lv  = (const float*)d_in[10];
    const float* W_dec = (const float*)d_in[11];
    const float* b_dec = (const float*)d_in[12];
    const float* W2    = (const float*)d_in[13];
    const float* b2    = (const float*)d_in[14];
    float* out = (float*)d_out;

    // workspace layout
    float* support1 = (float*)d_ws;                                        // 12.8M f32
    float* h1f      = support1 + (size_t)N_NODES * NHID;                   // 12.8M f32
    unsigned short* x1cat = (unsigned short*)(h1f + (size_t)N_NODES * NHID);  // 25.6M u16
    float* support2 = (float*)(x1cat + (size_t)N_NODES * 2 * NHID);        // 2M f32
    unsigned short* W1t  = (unsigned short*)(support2 + (size_t)N_NODES * NCLASS);
    unsigned short* W2bt = W1t + (size_t)NHID * NFEAT;                     // 24576 u16
    int*   counts   = (int*)(W2bt + (size_t)NCLS_PAD * NFEAT);
    int*   offsets  = counts + N_NODES;
    int*   cursor   = offsets + N_NODES + 1;
    int*   src_s    = cursor + N_NODES;
    float* w_s      = (float*)(src_s + N_EDGES);
    size_t need = (size_t)((char*)(w_s + N_EDGES) - (char*)d_ws);
    if (ws_size < need) return;

    hipMemsetAsync(counts, 0, N_NODES * sizeof(int), stream);
    hipMemsetAsync(cursor, 0, N_NODES * sizeof(int), stream);
    hist_kernel<<<(N_EDGES + 255) / 256, 256, 0, stream>>>(edst, counts);
    scan_kernel<<<1, 1024, 0, stream>>>(counts, offsets);
    scatter_kernel<<<(N_EDGES + 255) / 256, 256, 0, stream>>>(edst, esrc, ew, offsets, cursor,
                                                              src_s, w_s);

    w1t_kernel<<<(NFEAT * NHID + 255) / 256, 256, 0, stream>>>(W1, W1t);
    w2t_kernel<<<(NCLS_PAD * NFEAT + 255) / 256, 256, 0, stream>>>(W2, W2bt);
    gemm1_mfma<<<(N_NODES + 63) / 64, 256, 0, stream>>>(x, W1t, support1);
    spmm1_kernel<<<N_NODES / 4, 256, 0, stream>>>(offsets, src_s, w_s, support1, b1, h1f, x1cat);
    mlp_kernel<<<N_NODES / 16, 256, 0, stream>>>(h1f, eps, W_mu, b_mu, W_lv, b_lv, W_dec, b_dec,
                                                 x1cat);
    gemm2_mfma<<<(N_NODES + 63) / 64, 256, 0, stream>>>(x1cat, W2bt, support2);
    spmm2_softmax_kernel<<<N_NODES / 4, 256, 0, stream>>>(offsets, src_s, w_s, support2, b2, out);
}

// Round 4
// 646.041 us; speedup vs baseline: 1.2741x; 1.2741x over previous
//
#include <hip/hip_runtime.h>
#include <math.h>

#define N_NODES 50000
#define N_EDGES 800000
#define NFEAT 512
#define NHID 256
#define NCODE 64
#define NCLASS 40
#define NCLS_PAD 48

typedef __attribute__((ext_vector_type(8))) short short8;
typedef __attribute__((ext_vector_type(8))) unsigned short ushort8;
typedef __attribute__((ext_vector_type(4))) unsigned short ushort4v;
typedef __attribute__((ext_vector_type(4))) float floatx4;

__device__ inline unsigned short f2bf(float f) {
    unsigned u = __builtin_bit_cast(unsigned, f);
    u += 0x7fff + ((u >> 16) & 1);
    return (unsigned short)(u >> 16);
}

// ---------------- CSR build (by dst) ----------------
__global__ __launch_bounds__(256) void hist_kernel(const int* __restrict__ dst,
                                                   int* __restrict__ counts) {
    int t = blockIdx.x * 256 + threadIdx.x;
    if (t < N_EDGES) atomicAdd(&counts[dst[t]], 1);
}

__global__ __launch_bounds__(1024) void scan_kernel(const int* __restrict__ counts,
                                                    int* __restrict__ offsets) {
    __shared__ int sums[1024];
    int t = threadIdx.x;
    const int CH = (N_NODES + 1023) / 1024;  // 49
    int start = t * CH;
    int end = min(start + CH, N_NODES);
    int s = 0;
    for (int i = start; i < end; i++) s += counts[i];
    sums[t] = s;
    __syncthreads();
    for (int off = 1; off < 1024; off <<= 1) {
        int v = (t >= off) ? sums[t - off] : 0;
        __syncthreads();
        sums[t] += v;
        __syncthreads();
    }
    int run = (t == 0) ? 0 : sums[t - 1];
    for (int i = start; i < end; i++) {
        offsets[i] = run;
        run += counts[i];
    }
    if (t == 1023) offsets[N_NODES] = sums[1023];
}

__global__ __launch_bounds__(256) void scatter_kernel(const int* __restrict__ dst,
                                                      const int* __restrict__ src,
                                                      const float* __restrict__ w,
                                                      const int* __restrict__ offsets,
                                                      int* __restrict__ cursor,
                                                      int* __restrict__ src_s,
                                                      float* __restrict__ w_s) {
    int t = blockIdx.x * 256 + threadIdx.x;
    if (t < N_EDGES) {
        int d = dst[t];
        int pos = offsets[d] + atomicAdd(&cursor[d], 1);
        src_s[pos] = src[t];
        w_s[pos] = w[t];
    }
}

// ---------------- W1 transpose+cast: W1[512][256] f32 -> W1t[256][512] bf16 ----------------
__global__ __launch_bounds__(256) void w1t_kernel(const float* __restrict__ W1,
                                                  unsigned short* __restrict__ W1t) {
    int idx = blockIdx.x * 256 + threadIdx.x;
    if (idx < NFEAT * NHID) {
        int k = idx >> 8;
        int n = idx & 255;
        W1t[(size_t)n * NFEAT + k] = f2bf(W1[idx]);
    }
}

// ---------------- W2 transpose+cast+pad: W2[512][40] f32 -> W2bt[48][512] bf16 ----------------
__global__ __launch_bounds__(256) void w2t_kernel(const float* __restrict__ W2,
                                                  unsigned short* __restrict__ W2bt) {
    int idx = blockIdx.x * 256 + threadIdx.x;  // 48*512
    if (idx < NCLS_PAD * NFEAT) {
        int n = idx >> 9;
        int k = idx & 511;
        W2bt[idx] = (n < NCLASS) ? f2bf(W2[(size_t)k * NCLASS + n]) : (unsigned short)0;
    }
}

// ---------------- MLP weight prep: W_mulvt[128][256], W_dect[256][64] (bf16, transposed) ----------
__global__ __launch_bounds__(256) void wmlp_kernel(const float* __restrict__ W_mu,
                                                   const float* __restrict__ W_lv,
                                                   const float* __restrict__ W_dec,
                                                   unsigned short* __restrict__ W_mulvt,
                                                   unsigned short* __restrict__ W_dect) {
    int idx = blockIdx.x * 256 + threadIdx.x;
    if (idx < 128 * 256) {
        int j = idx >> 8;    // 0..127 output col
        int k = idx & 255;   // 0..255
        float v = (j < 64) ? W_mu[(size_t)k * NCODE + j] : W_lv[(size_t)k * NCODE + (j - 64)];
        W_mulvt[(size_t)j * 256 + k] = f2bf(v);
    } else if (idx < 128 * 256 + 256 * 64) {
        int i2 = idx - 128 * 256;
        int n = i2 >> 6;     // 0..255 output col
        int k = i2 & 63;     // 0..63
        W_dect[(size_t)n * 64 + k] = f2bf(W_dec[(size_t)k * NHID + n]);
    }
}

// ---------------- GEMM1 (bf16 MFMA): support1 = x @ W1 ----------------
__global__ __launch_bounds__(256) void gemm1_mfma(const float* __restrict__ A,
                                                  const unsigned short* __restrict__ Bt,
                                                  float* __restrict__ C) {
    __shared__ unsigned short As[64][40];
    __shared__ unsigned short Bs[256][40];
    int t = threadIdx.x;
    int wave = t >> 6, lane = t & 63;
    int quad = lane >> 4, m16 = lane & 15;
    int m0 = blockIdx.x * 64;

    floatx4 acc[16];
#pragma unroll
    for (int i = 0; i < 16; i++) acc[i] = (floatx4){0.f, 0.f, 0.f, 0.f};

    int ar = t >> 2;
    int ako = (t & 3) * 8;
    int arow = m0 + ar;
    if (arow >= N_NODES) arow = N_NODES - 1;
    const float* Abase = A + (size_t)arow * NFEAT + ako;
    const unsigned short* Bbase = Bt + (size_t)t * NFEAT;

    for (int k0 = 0; k0 < NFEAT; k0 += 32) {
        float4 a0 = *(const float4*)(Abase + k0);
        float4 a1 = *(const float4*)(Abase + k0 + 4);
        ushort8 b0 = *(const ushort8*)(Bbase + k0);
        ushort8 b1 = *(const ushort8*)(Bbase + k0 + 8);
        ushort8 b2 = *(const ushort8*)(Bbase + k0 + 16);
        ushort8 b3 = *(const ushort8*)(Bbase + k0 + 24);
        __syncthreads();
        ushort8 av;
        av[0] = f2bf(a0.x); av[1] = f2bf(a0.y); av[2] = f2bf(a0.z); av[3] = f2bf(a0.w);
        av[4] = f2bf(a1.x); av[5] = f2bf(a1.y); av[6] = f2bf(a1.z); av[7] = f2bf(a1.w);
        *(ushort8*)&As[ar][ako] = av;
        *(ushort8*)&Bs[t][0]  = b0;
        *(ushort8*)&Bs[t][8]  = b1;
        *(ushort8*)&Bs[t][16] = b2;
        *(ushort8*)&Bs[t][24] = b3;
        __syncthreads();
        short8 afrag = *(const short8*)&As[wave * 16 + m16][quad * 8];
#pragma unroll
        for (int nt = 0; nt < 16; nt++) {
            short8 bfrag = *(const short8*)&Bs[nt * 16 + m16][quad * 8];
            acc[nt] = __builtin_amdgcn_mfma_f32_16x16x32_bf16(afrag, bfrag, acc[nt], 0, 0, 0);
        }
    }
#pragma unroll
    for (int nt = 0; nt < 16; nt++) {
#pragma unroll
        for (int r = 0; r < 4; r++) {
            int row = m0 + wave * 16 + quad * 4 + r;
            int col = nt * 16 + m16;
            if (row < N_NODES) C[(size_t)row * NHID + col] = acc[nt][r];
        }
    }
}

// ---------------- SpMM1 + bias + relu -> x1cat[:,256:512] (bf16) ----------------
__global__ __launch_bounds__(256) void spmm1_kernel(const int* __restrict__ offsets,
                                                    const int* __restrict__ src_s,
                                                    const float* __restrict__ w_s,
                                                    const float* __restrict__ support1,
                                                    const float* __restrict__ b1,
                                                    unsigned short* __restrict__ x1cat) {
    int n = blockIdx.x * 4 + (threadIdx.x >> 6);
    int lane = threadIdx.x & 63;
    int beg = offsets[n], end = offsets[n + 1];
    float ax = 0.f, ay = 0.f, az = 0.f, aw = 0.f;
    int i = beg;
    for (; i + 4 <= end; i += 4) {
        int s0 = src_s[i], s1 = src_s[i + 1], s2 = src_s[i + 2], s3 = src_s[i + 3];
        float w0 = w_s[i], w1 = w_s[i + 1], w2 = w_s[i + 2], w3 = w_s[i + 3];
        float4 r0 = *(const float4*)&support1[(size_t)s0 * NHID + lane * 4];
        float4 r1 = *(const float4*)&support1[(size_t)s1 * NHID + lane * 4];
        float4 r2 = *(const float4*)&support1[(size_t)s2 * NHID + lane * 4];
        float4 r3 = *(const float4*)&support1[(size_t)s3 * NHID + lane * 4];
        ax += w0 * r0.x + w1 * r1.x + w2 * r2.x + w3 * r3.x;
        ay += w0 * r0.y + w1 * r1.y + w2 * r2.y + w3 * r3.y;
        az += w0 * r0.z + w1 * r1.z + w2 * r2.z + w3 * r3.z;
        aw += w0 * r0.w + w1 * r1.w + w2 * r2.w + w3 * r3.w;
    }
    for (; i < end; i++) {
        int s = src_s[i];
        float ww = w_s[i];
        float4 r = *(const float4*)&support1[(size_t)s * NHID + lane * 4];
        ax += ww * r.x; ay += ww * r.y; az += ww * r.z; aw += ww * r.w;
    }
    float4 bb = *(const float4*)&b1[lane * 4];
    ushort4v hb;
    hb[0] = f2bf(fmaxf(ax + bb.x, 0.f));
    hb[1] = f2bf(fmaxf(ay + bb.y, 0.f));
    hb[2] = f2bf(fmaxf(az + bb.z, 0.f));
    hb[3] = f2bf(fmaxf(aw + bb.w, 0.f));
    *(ushort4v*)&x1cat[(size_t)n * (2 * NHID) + NHID + lane * 4] = hb;
}

// ---------------- Fused MLP via MFMA: 16 nodes/block ----------------
// phase A: mu||lv = h1(bf16, from x1cat) @ W_mulvt    [16x256]@[256x128]
// phase B: z = mu + eps*exp(lv)  -> LDS bf16
// phase C: x1 = relu(z @ W_dect + b_dec) -> x1cat[:,0:256] bf16
__global__ __launch_bounds__(256) void mlp_mfma(const unsigned short* __restrict__ x1cat_ro,
                                                const float* __restrict__ eps,
                                                const float* __restrict__ b_mu,
                                                const float* __restrict__ b_lv,
                                                const unsigned short* __restrict__ W_mulvt,
                                                const float* __restrict__ b_dec,
                                                const unsigned short* __restrict__ W_dect,
                                                unsigned short* __restrict__ x1cat) {
    __shared__ float smulv[16][132];          // mu (0..63) | lv (64..127), pitch 132
    __shared__ unsigned short z_bf[16][72];   // z bf16, pitch 72
    int t = threadIdx.x;
    int wave = t >> 6, lane = t & 63;
    int quad = lane >> 4, m16 = lane & 15;
    int node0 = blockIdx.x * 16;

    // ---- phase A ----
    {
        floatx4 acc[2];
        acc[0] = (floatx4){0.f, 0.f, 0.f, 0.f};
        acc[1] = (floatx4){0.f, 0.f, 0.f, 0.f};
        const unsigned short* Abase =
            x1cat_ro + (size_t)(node0 + m16) * 512 + 256 + quad * 8;
        const unsigned short* Bb0 = W_mulvt + (size_t)(wave * 32 + m16) * 256 + quad * 8;
        const unsigned short* Bb1 = Bb0 + 16 * 256;
#pragma unroll
        for (int k0 = 0; k0 < 256; k0 += 32) {
            short8 afrag = *(const short8*)(Abase + k0);
            short8 bf0 = *(const short8*)(Bb0 + k0);
            short8 bf1 = *(const short8*)(Bb1 + k0);
            acc[0] = __builtin_amdgcn_mfma_f32_16x16x32_bf16(afrag, bf0, acc[0], 0, 0, 0);
            acc[1] = __builtin_amdgcn_mfma_f32_16x16x32_bf16(afrag, bf1, acc[1], 0, 0, 0);
        }
#pragma unroll
        for (int nt = 0; nt < 2; nt++) {
            int j = wave * 32 + nt * 16 + m16;  // 0..127
            float bias = (j < 64) ? b_mu[j] : b_lv[j - 64];
#pragma unroll
            for (int r = 0; r < 4; r++)
                smulv[quad * 4 + r][j] = acc[nt][r] + bias;
        }
    }
    __syncthreads();
    // ---- phase B ----
#pragma unroll
    for (int r = 0; r < 4; r++) {
        int idx = t + r * 256;
        int n = idx >> 6, j = idx & 63;
        float z = smulv[n][j] + eps[(size_t)node0 * NCODE + idx] * expf(smulv[n][64 + j]);
        z_bf[n][j] = f2bf(z);
    }
    __syncthreads();
    // ---- phase C ----
    {
        floatx4 acc[4];
#pragma unroll
        for (int i = 0; i < 4; i++) acc[i] = (floatx4){0.f, 0.f, 0.f, 0.f};
#pragma unroll
        for (int ks = 0; ks < 2; ks++) {
            int k0 = ks * 32;
            short8 afrag = *(const short8*)&z_bf[m16][k0 + quad * 8];
#pragma unroll
            for (int nt = 0; nt < 4; nt++) {
                int col = wave * 64 + nt * 16 + m16;
                short8 bfrag = *(const short8*)(W_dect + (size_t)col * 64 + k0 + quad * 8);
                acc[nt] = __builtin_amdgcn_mfma_f32_16x16x32_bf16(afrag, bfrag, acc[nt], 0, 0, 0);
            }
        }
#pragma unroll
        for (int nt = 0; nt < 4; nt++) {
            int col = wave * 64 + nt * 16 + m16;
            float bias = b_dec[col];
#pragma unroll
            for (int r = 0; r < 4; r++) {
                int node = node0 + quad * 4 + r;
                x1cat[(size_t)node * 512 + col] = f2bf(fmaxf(acc[nt][r] + bias, 0.f));
            }
        }
    }
}

// ---------------- GEMM2 (bf16 MFMA): support2 = x1cat @ W2 ----------------
__global__ __launch_bounds__(256) void gemm2_mfma(const unsigned short* __restrict__ Xb,
                                                  const unsigned short* __restrict__ Bt,
                                                  float* __restrict__ S2) {
    __shared__ unsigned short As[64][40];
    __shared__ unsigned short Bs[48][40];
    int t = threadIdx.x;
    int wave = t >> 6, lane = t & 63;
    int quad = lane >> 4, m16 = lane & 15;
    int m0 = blockIdx.x * 64;

    floatx4 acc[3];
#pragma unroll
    for (int i = 0; i < 3; i++) acc[i] = (floatx4){0.f, 0.f, 0.f, 0.f};

    int ar = t >> 2;
    int ako = (t & 3) * 8;
    int arow = m0 + ar;
    if (arow >= N_NODES) arow = N_NODES - 1;
    const unsigned short* Abase = Xb + (size_t)arow * NFEAT + ako;
    const unsigned short* Bbase = Bt + (size_t)(t >> 2) * NFEAT + ako;

    for (int k0 = 0; k0 < NFEAT; k0 += 32) {
        ushort8 a0 = *(const ushort8*)(Abase + k0);
        ushort8 b0;
        if ((t >> 2) < NCLS_PAD) b0 = *(const ushort8*)(Bbase + k0);
        __syncthreads();
        *(ushort8*)&As[ar][ako] = a0;
        if ((t >> 2) < NCLS_PAD) *(ushort8*)&Bs[t >> 2][ako] = b0;
        __syncthreads();
        short8 afrag = *(const short8*)&As[wave * 16 + m16][quad * 8];
#pragma unroll
        for (int nt = 0; nt < 3; nt++) {
            short8 bfrag = *(const short8*)&Bs[nt * 16 + m16][quad * 8];
            acc[nt] = __builtin_amdgcn_mfma_f32_16x16x32_bf16(afrag, bfrag, acc[nt], 0, 0, 0);
        }
    }
#pragma unroll
    for (int nt = 0; nt < 3; nt++) {
        int col = nt * 16 + m16;
        if (col < NCLASS) {
#pragma unroll
            for (int r = 0; r < 4; r++) {
                int row = m0 + wave * 16 + quad * 4 + r;
                if (row < N_NODES) S2[(size_t)row * NCLASS + col] = acc[nt][r];
            }
        }
    }
}

// ---------------- SpMM2 + bias + log_softmax -> out ----------------
__global__ __launch_bounds__(256) void spmm2_softmax_kernel(const int* __restrict__ offsets,
                                                            const int* __restrict__ src_s,
                                                            const float* __restrict__ w_s,
                                                            const float* __restrict__ S2,
                                                            const float* __restrict__ b2,
                                                            float* __restrict__ out) {
    int wave = threadIdx.x >> 6;
    int lane = threadIdx.x & 63;
    int n = blockIdx.x * 4 + wave;
    int beg = offsets[n], end = offsets[n + 1];
    float acc = 0.f;
    int i = beg;
    for (; i + 2 <= end; i += 2) {
        int s0 = src_s[i], s1 = src_s[i + 1];
        float w0 = w_s[i], w1 = w_s[i + 1];
        if (lane < NCLASS) {
            float v0 = S2[(size_t)s0 * NCLASS + lane];
            float v1 = S2[(size_t)s1 * NCLASS + lane];
            acc += w0 * v0 + w1 * v1;
        }
    }
    for (; i < end; i++) {
        int s = src_s[i];
        float ww = w_s[i];
        if (lane < NCLASS) acc += ww * S2[(size_t)s * NCLASS + lane];
    }
    float v = (lane < NCLASS) ? (acc + b2[lane]) : -INFINITY;
    float m = v;
#pragma unroll
    for (int off = 32; off > 0; off >>= 1) m = fmaxf(m, __shfl_xor(m, off));
    float ex = (lane < NCLASS) ? expf(v - m) : 0.f;
    float ssum = ex;
#pragma unroll
    for (int off = 32; off > 0; off >>= 1) ssum += __shfl_xor(ssum, off);
    if (lane < NCLASS) out[(size_t)n * NCLASS + lane] = v - m - logf(ssum);
}

extern "C" void kernel_launch(void* const* d_in, const int* in_sizes, int n_in,
                              void* d_out, int out_size, void* d_ws, size_t ws_size,
                              hipStream_t stream) {
    const float* x     = (const float*)d_in[0];
    const int*   esrc  = (const int*)d_in[1];
    const int*   edst  = (const int*)d_in[2];
    const float* ew    = (const float*)d_in[3];
    const float* eps   = (const float*)d_in[4];
    const float* W1    = (const float*)d_in[5];
    const float* b1    = (const float*)d_in[6];
    const float* W_mu  = (const float*)d_in[7];
    const float* b_mu  = (const float*)d_in[8];
    const float* W_lv  = (const float*)d_in[9];
    const float* b_lv  = (const float*)d_in[10];
    const float* W_dec = (const float*)d_in[11];
    const float* b_dec = (const float*)d_in[12];
    const float* W2    = (const float*)d_in[13];
    const float* b2    = (const float*)d_in[14];
    float* out = (float*)d_out;

    // workspace layout
    float* support1 = (float*)d_ws;                                        // 12.8M f32
    unsigned short* x1cat = (unsigned short*)(support1 + (size_t)N_NODES * NHID);  // 25.6M u16
    float* support2 = (float*)(x1cat + (size_t)N_NODES * 2 * NHID);        // 2M f32
    unsigned short* W1t    = (unsigned short*)(support2 + (size_t)N_NODES * NCLASS);
    unsigned short* W2bt   = W1t + (size_t)NHID * NFEAT;
    unsigned short* W_mulvt = W2bt + (size_t)NCLS_PAD * NFEAT;             // 32768 u16
    unsigned short* W_dect  = W_mulvt + 128 * 256;                         // 16384 u16
    int*   counts   = (int*)(W_dect + 256 * 64);
    int*   offsets  = counts + N_NODES;
    int*   cursor   = offsets + N_NODES + 1;
    int*   src_s    = cursor + N_NODES;
    float* w_s      = (float*)(src_s + N_EDGES);
    size_t need = (size_t)((char*)(w_s + N_EDGES) - (char*)d_ws);
    if (ws_size < need) return;

    hipMemsetAsync(counts, 0, N_NODES * sizeof(int), stream);
    hipMemsetAsync(cursor, 0, N_NODES * sizeof(int), stream);
    hist_kernel<<<(N_EDGES + 255) / 256, 256, 0, stream>>>(edst, counts);
    scan_kernel<<<1, 1024, 0, stream>>>(counts, offsets);
    scatter_kernel<<<(N_EDGES + 255) / 256, 256, 0, stream>>>(edst, esrc, ew, offsets, cursor,
                                                              src_s, w_s);

    w1t_kernel<<<(NFEAT * NHID + 255) / 256, 256, 0, stream>>>(W1, W1t);
    w2t_kernel<<<(NCLS_PAD * NFEAT + 255) / 256, 256, 0, stream>>>(W2, W2bt);
    wmlp_kernel<<<(128 * 256 + 256 * 64 + 255) / 256, 256, 0, stream>>>(W_mu, W_lv, W_dec,
                                                                        W_mulvt, W_dect);
    gemm1_mfma<<<(N_NODES + 63) / 64, 256, 0, stream>>>(x, W1t, support1);
    spmm1_kernel<<<N_NODES / 4, 256, 0, stream>>>(offsets, src_s, w_s, support1, b1, x1cat);
    mlp_mfma<<<N_NODES / 16, 256, 0, stream>>>(x1cat, eps, b_mu, b_lv, W_mulvt, b_dec, W_dect,
                                               x1cat);
    gemm2_mfma<<<(N_NODES + 63) / 64, 256, 0, stream>>>(x1cat, W2bt, support2);
    spmm2_softmax_kernel<<<N_NODES / 4, 256, 0, stream>>>(offsets, src_s, w_s, support2, b2, out);
}

// Round 5
// 567.088 us; speedup vs baseline: 1.4515x; 1.1392x over previous
//
#include <hip/hip_runtime.h>
#include <math.h>

#define N_NODES 50000
#define N_EDGES 800000
#define NFEAT 512
#define NHID 256
#define NCODE 64
#define NCLASS 40
#define NCLS_PAD 48

typedef __attribute__((ext_vector_type(8))) short short8;
typedef __attribute__((ext_vector_type(8))) unsigned short ushort8;
typedef __attribute__((ext_vector_type(4))) unsigned short ushort4v;
typedef __attribute__((ext_vector_type(4))) float floatx4;

__device__ inline unsigned short f2bf(float f) {
    unsigned u = __builtin_bit_cast(unsigned, f);
    u += 0x7fff + ((u >> 16) & 1);
    return (unsigned short)(u >> 16);
}
__device__ inline float bf2f(unsigned short h) {
    return __builtin_bit_cast(float, (unsigned)h << 16);
}

// ---------------- CSR build (by dst) ----------------
__global__ __launch_bounds__(256) void hist_kernel(const int* __restrict__ dst,
                                                   int* __restrict__ counts) {
    int t = blockIdx.x * 256 + threadIdx.x;
    if (t < N_EDGES) atomicAdd(&counts[dst[t]], 1);
}

__global__ __launch_bounds__(1024) void scan_kernel(const int* __restrict__ counts,
                                                    int* __restrict__ offsets) {
    __shared__ int sums[1024];
    int t = threadIdx.x;
    const int CH = (N_NODES + 1023) / 1024;  // 49
    int start = t * CH;
    int end = min(start + CH, N_NODES);
    int s = 0;
    for (int i = start; i < end; i++) s += counts[i];
    sums[t] = s;
    __syncthreads();
    for (int off = 1; off < 1024; off <<= 1) {
        int v = (t >= off) ? sums[t - off] : 0;
        __syncthreads();
        sums[t] += v;
        __syncthreads();
    }
    int run = (t == 0) ? 0 : sums[t - 1];
    for (int i = start; i < end; i++) {
        offsets[i] = run;
        run += counts[i];
    }
    if (t == 1023) offsets[N_NODES] = sums[1023];
}

// scatter edges into dst-sorted order as packed (src, w_bits) int2
__global__ __launch_bounds__(256) void scatter_kernel(const int* __restrict__ dst,
                                                      const int* __restrict__ src,
                                                      const float* __restrict__ w,
                                                      const int* __restrict__ offsets,
                                                      int* __restrict__ cursor,
                                                      int2* __restrict__ edges) {
    int t = blockIdx.x * 256 + threadIdx.x;
    if (t < N_EDGES) {
        int d = dst[t];
        int pos = offsets[d] + atomicAdd(&cursor[d], 1);
        edges[pos] = make_int2(src[t], __builtin_bit_cast(int, w[t]));
    }
}

// ---------------- W1 transpose+cast: W1[512][256] f32 -> W1t[256][512] bf16 ----------------
__global__ __launch_bounds__(256) void w1t_kernel(const float* __restrict__ W1,
                                                  unsigned short* __restrict__ W1t) {
    int idx = blockIdx.x * 256 + threadIdx.x;
    if (idx < NFEAT * NHID) {
        int k = idx >> 8;
        int n = idx & 255;
        W1t[(size_t)n * NFEAT + k] = f2bf(W1[idx]);
    }
}

// ---------------- W2 transpose+cast+pad: W2[512][40] f32 -> W2bt[48][512] bf16 ----------------
__global__ __launch_bounds__(256) void w2t_kernel(const float* __restrict__ W2,
                                                  unsigned short* __restrict__ W2bt) {
    int idx = blockIdx.x * 256 + threadIdx.x;  // 48*512
    if (idx < NCLS_PAD * NFEAT) {
        int n = idx >> 9;
        int k = idx & 511;
        W2bt[idx] = (n < NCLASS) ? f2bf(W2[(size_t)k * NCLASS + n]) : (unsigned short)0;
    }
}

// ---------------- MLP weight prep: W_mulvt[128][256], W_dect[256][64] (bf16, transposed) ----------
__global__ __launch_bounds__(256) void wmlp_kernel(const float* __restrict__ W_mu,
                                                   const float* __restrict__ W_lv,
                                                   const float* __restrict__ W_dec,
                                                   unsigned short* __restrict__ W_mulvt,
                                                   unsigned short* __restrict__ W_dect) {
    int idx = blockIdx.x * 256 + threadIdx.x;
    if (idx < 128 * 256) {
        int j = idx >> 8;
        int k = idx & 255;
        float v = (j < 64) ? W_mu[(size_t)k * NCODE + j] : W_lv[(size_t)k * NCODE + (j - 64)];
        W_mulvt[(size_t)j * 256 + k] = f2bf(v);
    } else if (idx < 128 * 256 + 256 * 64) {
        int i2 = idx - 128 * 256;
        int n = i2 >> 6;
        int k = i2 & 63;
        W_dect[(size_t)n * 64 + k] = f2bf(W_dec[(size_t)k * NHID + n]);
    }
}

// ---------------- GEMM1 (bf16 MFMA): support1b = bf16(x @ W1) ----------------
__global__ __launch_bounds__(256) void gemm1_mfma(const float* __restrict__ A,
                                                  const unsigned short* __restrict__ Bt,
                                                  unsigned short* __restrict__ C) {
    __shared__ unsigned short As[64][40];
    __shared__ unsigned short Bs[256][40];
    int t = threadIdx.x;
    int wave = t >> 6, lane = t & 63;
    int quad = lane >> 4, m16 = lane & 15;
    int m0 = blockIdx.x * 64;

    floatx4 acc[16];
#pragma unroll
    for (int i = 0; i < 16; i++) acc[i] = (floatx4){0.f, 0.f, 0.f, 0.f};

    int ar = t >> 2;
    int ako = (t & 3) * 8;
    int arow = m0 + ar;
    if (arow >= N_NODES) arow = N_NODES - 1;
    const float* Abase = A + (size_t)arow * NFEAT + ako;
    const unsigned short* Bbase = Bt + (size_t)t * NFEAT;

    for (int k0 = 0; k0 < NFEAT; k0 += 32) {
        float4 a0 = *(const float4*)(Abase + k0);
        float4 a1 = *(const float4*)(Abase + k0 + 4);
        ushort8 b0 = *(const ushort8*)(Bbase + k0);
        ushort8 b1 = *(const ushort8*)(Bbase + k0 + 8);
        ushort8 b2 = *(const ushort8*)(Bbase + k0 + 16);
        ushort8 b3 = *(const ushort8*)(Bbase + k0 + 24);
        __syncthreads();
        ushort8 av;
        av[0] = f2bf(a0.x); av[1] = f2bf(a0.y); av[2] = f2bf(a0.z); av[3] = f2bf(a0.w);
        av[4] = f2bf(a1.x); av[5] = f2bf(a1.y); av[6] = f2bf(a1.z); av[7] = f2bf(a1.w);
        *(ushort8*)&As[ar][ako] = av;
        *(ushort8*)&Bs[t][0]  = b0;
        *(ushort8*)&Bs[t][8]  = b1;
        *(ushort8*)&Bs[t][16] = b2;
        *(ushort8*)&Bs[t][24] = b3;
        __syncthreads();
        short8 afrag = *(const short8*)&As[wave * 16 + m16][quad * 8];
#pragma unroll
        for (int nt = 0; nt < 16; nt++) {
            short8 bfrag = *(const short8*)&Bs[nt * 16 + m16][quad * 8];
            acc[nt] = __builtin_amdgcn_mfma_f32_16x16x32_bf16(afrag, bfrag, acc[nt], 0, 0, 0);
        }
    }
    // epilogue: bf16 stores (per-wave 32B segments; L2 merges into full lines)
#pragma unroll
    for (int nt = 0; nt < 16; nt++) {
        int col = nt * 16 + m16;
#pragma unroll
        for (int r = 0; r < 4; r++) {
            int row = m0 + wave * 16 + quad * 4 + r;
            if (row < N_NODES) C[(size_t)row * NHID + col] = f2bf(acc[nt][r]);
        }
    }
}

// ---------------- SpMM1 + bias + relu -> x1cat[:,256:512] (bf16) ----------------
// one wave per node; lane covers 4 feats as ushort4 (8B); 4-edge unroll
__global__ __launch_bounds__(256) void spmm1_kernel(const int* __restrict__ offsets,
                                                    const int2* __restrict__ edges,
                                                    const unsigned short* __restrict__ S1b,
                                                    const float* __restrict__ b1,
                                                    unsigned short* __restrict__ x1cat) {
    int n = blockIdx.x * 4 + (threadIdx.x >> 6);
    int lane = threadIdx.x & 63;
    int beg = offsets[n], end = offsets[n + 1];
    float ax = 0.f, ay = 0.f, az = 0.f, aw = 0.f;
    int i = beg;
    for (; i + 4 <= end; i += 4) {
        int2 e0 = edges[i], e1 = edges[i + 1], e2 = edges[i + 2], e3 = edges[i + 3];
        float w0 = __builtin_bit_cast(float, e0.y);
        float w1 = __builtin_bit_cast(float, e1.y);
        float w2 = __builtin_bit_cast(float, e2.y);
        float w3 = __builtin_bit_cast(float, e3.y);
        ushort4v r0 = *(const ushort4v*)&S1b[(size_t)e0.x * NHID + lane * 4];
        ushort4v r1 = *(const ushort4v*)&S1b[(size_t)e1.x * NHID + lane * 4];
        ushort4v r2 = *(const ushort4v*)&S1b[(size_t)e2.x * NHID + lane * 4];
        ushort4v r3 = *(const ushort4v*)&S1b[(size_t)e3.x * NHID + lane * 4];
        ax += w0 * bf2f(r0[0]) + w1 * bf2f(r1[0]) + w2 * bf2f(r2[0]) + w3 * bf2f(r3[0]);
        ay += w0 * bf2f(r0[1]) + w1 * bf2f(r1[1]) + w2 * bf2f(r2[1]) + w3 * bf2f(r3[1]);
        az += w0 * bf2f(r0[2]) + w1 * bf2f(r1[2]) + w2 * bf2f(r2[2]) + w3 * bf2f(r3[2]);
        aw += w0 * bf2f(r0[3]) + w1 * bf2f(r1[3]) + w2 * bf2f(r2[3]) + w3 * bf2f(r3[3]);
    }
    for (; i < end; i++) {
        int2 e = edges[i];
        float ww = __builtin_bit_cast(float, e.y);
        ushort4v r = *(const ushort4v*)&S1b[(size_t)e.x * NHID + lane * 4];
        ax += ww * bf2f(r[0]); ay += ww * bf2f(r[1]);
        az += ww * bf2f(r[2]); aw += ww * bf2f(r[3]);
    }
    float4 bb = *(const float4*)&b1[lane * 4];
    ushort4v hb;
    hb[0] = f2bf(fmaxf(ax + bb.x, 0.f));
    hb[1] = f2bf(fmaxf(ay + bb.y, 0.f));
    hb[2] = f2bf(fmaxf(az + bb.z, 0.f));
    hb[3] = f2bf(fmaxf(aw + bb.w, 0.f));
    *(ushort4v*)&x1cat[(size_t)n * (2 * NHID) + NHID + lane * 4] = hb;
}

// ---------------- Fused MLP via MFMA: 16 nodes/block ----------------
__global__ __launch_bounds__(256) void mlp_mfma(const unsigned short* __restrict__ x1cat_ro,
                                                const float* __restrict__ eps,
                                                const float* __restrict__ b_mu,
                                                const float* __restrict__ b_lv,
                                                const unsigned short* __restrict__ W_mulvt,
                                                const float* __restrict__ b_dec,
                                                const unsigned short* __restrict__ W_dect,
                                                unsigned short* __restrict__ x1cat) {
    __shared__ float smulv[16][132];
    __shared__ unsigned short z_bf[16][72];
    int t = threadIdx.x;
    int wave = t >> 6, lane = t & 63;
    int quad = lane >> 4, m16 = lane & 15;
    int node0 = blockIdx.x * 16;

    // ---- phase A: mu||lv = h1 @ W_mulvt ----
    {
        floatx4 acc[2];
        acc[0] = (floatx4){0.f, 0.f, 0.f, 0.f};
        acc[1] = (floatx4){0.f, 0.f, 0.f, 0.f};
        const unsigned short* Abase =
            x1cat_ro + (size_t)(node0 + m16) * 512 + 256 + quad * 8;
        const unsigned short* Bb0 = W_mulvt + (size_t)(wave * 32 + m16) * 256 + quad * 8;
        const unsigned short* Bb1 = Bb0 + 16 * 256;
#pragma unroll
        for (int k0 = 0; k0 < 256; k0 += 32) {
            short8 afrag = *(const short8*)(Abase + k0);
            short8 bf0 = *(const short8*)(Bb0 + k0);
            short8 bf1 = *(const short8*)(Bb1 + k0);
            acc[0] = __builtin_amdgcn_mfma_f32_16x16x32_bf16(afrag, bf0, acc[0], 0, 0, 0);
            acc[1] = __builtin_amdgcn_mfma_f32_16x16x32_bf16(afrag, bf1, acc[1], 0, 0, 0);
        }
#pragma unroll
        for (int nt = 0; nt < 2; nt++) {
            int j = wave * 32 + nt * 16 + m16;
            float bias = (j < 64) ? b_mu[j] : b_lv[j - 64];
#pragma unroll
            for (int r = 0; r < 4; r++)
                smulv[quad * 4 + r][j] = acc[nt][r] + bias;
        }
    }
    __syncthreads();
    // ---- phase B: z = mu + eps*exp(lv) ----
#pragma unroll
    for (int r = 0; r < 4; r++) {
        int idx = t + r * 256;
        int n = idx >> 6, j = idx & 63;
        float z = smulv[n][j] + eps[(size_t)node0 * NCODE + idx] * expf(smulv[n][64 + j]);
        z_bf[n][j] = f2bf(z);
    }
    __syncthreads();
    // ---- phase C: x1 = relu(z @ W_dect + b_dec) ----
    {
        floatx4 acc[4];
#pragma unroll
        for (int i = 0; i < 4; i++) acc[i] = (floatx4){0.f, 0.f, 0.f, 0.f};
#pragma unroll
        for (int ks = 0; ks < 2; ks++) {
            int k0 = ks * 32;
            short8 afrag = *(const short8*)&z_bf[m16][k0 + quad * 8];
#pragma unroll
            for (int nt = 0; nt < 4; nt++) {
                int col = wave * 64 + nt * 16 + m16;
                short8 bfrag = *(const short8*)(W_dect + (size_t)col * 64 + k0 + quad * 8);
                acc[nt] = __builtin_amdgcn_mfma_f32_16x16x32_bf16(afrag, bfrag, acc[nt], 0, 0, 0);
            }
        }
#pragma unroll
        for (int nt = 0; nt < 4; nt++) {
            int col = wave * 64 + nt * 16 + m16;
            float bias = b_dec[col];
#pragma unroll
            for (int r = 0; r < 4; r++) {
                int node = node0 + quad * 4 + r;
                x1cat[(size_t)node * 512 + col] = f2bf(fmaxf(acc[nt][r] + bias, 0.f));
            }
        }
    }
}

// ---------------- GEMM2 (bf16 MFMA): support2 = x1cat @ W2 ----------------
__global__ __launch_bounds__(256) void gemm2_mfma(const unsigned short* __restrict__ Xb,
                                                  const unsigned short* __restrict__ Bt,
                                                  float* __restrict__ S2) {
    __shared__ unsigned short As[64][40];
    __shared__ unsigned short Bs[48][40];
    int t = threadIdx.x;
    int wave = t >> 6, lane = t & 63;
    int quad = lane >> 4, m16 = lane & 15;
    int m0 = blockIdx.x * 64;

    floatx4 acc[3];
#pragma unroll
    for (int i = 0; i < 3; i++) acc[i] = (floatx4){0.f, 0.f, 0.f, 0.f};

    int ar = t >> 2;
    int ako = (t & 3) * 8;
    int arow = m0 + ar;
    if (arow >= N_NODES) arow = N_NODES - 1;
    const unsigned short* Abase = Xb + (size_t)arow * NFEAT + ako;
    const unsigned short* Bbase = Bt + (size_t)(t >> 2) * NFEAT + ako;

    for (int k0 = 0; k0 < NFEAT; k0 += 32) {
        ushort8 a0 = *(const ushort8*)(Abase + k0);
        ushort8 b0;
        if ((t >> 2) < NCLS_PAD) b0 = *(const ushort8*)(Bbase + k0);
        __syncthreads();
        *(ushort8*)&As[ar][ako] = a0;
        if ((t >> 2) < NCLS_PAD) *(ushort8*)&Bs[t >> 2][ako] = b0;
        __syncthreads();
        short8 afrag = *(const short8*)&As[wave * 16 + m16][quad * 8];
#pragma unroll
        for (int nt = 0; nt < 3; nt++) {
            short8 bfrag = *(const short8*)&Bs[nt * 16 + m16][quad * 8];
            acc[nt] = __builtin_amdgcn_mfma_f32_16x16x32_bf16(afrag, bfrag, acc[nt], 0, 0, 0);
        }
    }
#pragma unroll
    for (int nt = 0; nt < 3; nt++) {
        int col = nt * 16 + m16;
        if (col < NCLASS) {
#pragma unroll
            for (int r = 0; r < 4; r++) {
                int row = m0 + wave * 16 + quad * 4 + r;
                if (row < N_NODES) S2[(size_t)row * NCLASS + col] = acc[nt][r];
            }
        }
    }
}

// ---------------- SpMM2 + bias + log_softmax -> out ----------------
__global__ __launch_bounds__(256) void spmm2_softmax_kernel(const int* __restrict__ offsets,
                                                            const int2* __restrict__ edges,
                                                            const float* __restrict__ S2,
                                                            const float* __restrict__ b2,
                                                            float* __restrict__ out) {
    int wave = threadIdx.x >> 6;
    int lane = threadIdx.x & 63;
    int n = blockIdx.x * 4 + wave;
    int beg = offsets[n], end = offsets[n + 1];
    float acc = 0.f;
    int i = beg;
    for (; i + 2 <= end; i += 2) {
        int2 e0 = edges[i], e1 = edges[i + 1];
        float w0 = __builtin_bit_cast(float, e0.y);
        float w1 = __builtin_bit_cast(float, e1.y);
        if (lane < NCLASS) {
            float v0 = S2[(size_t)e0.x * NCLASS + lane];
            float v1 = S2[(size_t)e1.x * NCLASS + lane];
            acc += w0 * v0 + w1 * v1;
        }
    }
    for (; i < end; i++) {
        int2 e = edges[i];
        float ww = __builtin_bit_cast(float, e.y);
        if (lane < NCLASS) acc += ww * S2[(size_t)e.x * NCLASS + lane];
    }
    float v = (lane < NCLASS) ? (acc + b2[lane]) : -INFINITY;
    float m = v;
#pragma unroll
    for (int off = 32; off > 0; off >>= 1) m = fmaxf(m, __shfl_xor(m, off));
    float ex = (lane < NCLASS) ? expf(v - m) : 0.f;
    float ssum = ex;
#pragma unroll
    for (int off = 32; off > 0; off >>= 1) ssum += __shfl_xor(ssum, off);
    if (lane < NCLASS) out[(size_t)n * NCLASS + lane] = v - m - logf(ssum);
}

extern "C" void kernel_launch(void* const* d_in, const int* in_sizes, int n_in,
                              void* d_out, int out_size, void* d_ws, size_t ws_size,
                              hipStream_t stream) {
    const float* x     = (const float*)d_in[0];
    const int*   esrc  = (const int*)d_in[1];
    const int*   edst  = (const int*)d_in[2];
    const float* ew    = (const float*)d_in[3];
    const float* eps   = (const float*)d_in[4];
    const float* W1    = (const float*)d_in[5];
    const float* b1    = (const float*)d_in[6];
    const float* W_mu  = (const float*)d_in[7];
    const float* b_mu  = (const float*)d_in[8];
    const float* W_lv  = (const float*)d_in[9];
    const float* b_lv  = (const float*)d_in[10];
    const float* W_dec = (const float*)d_in[11];
    const float* b_dec = (const float*)d_in[12];
    const float* W2    = (const float*)d_in[13];
    const float* b2    = (const float*)d_in[14];
    float* out = (float*)d_out;

    // workspace layout
    unsigned short* support1b = (unsigned short*)d_ws;                     // 12.8M u16
    unsigned short* x1cat = support1b + (size_t)N_NODES * NHID;            // 25.6M u16
    float* support2 = (float*)(x1cat + (size_t)N_NODES * 2 * NHID);        // 2M f32
    unsigned short* W1t    = (unsigned short*)(support2 + (size_t)N_NODES * NCLASS);
    unsigned short* W2bt   = W1t + (size_t)NHID * NFEAT;
    unsigned short* W_mulvt = W2bt + (size_t)NCLS_PAD * NFEAT;
    unsigned short* W_dect  = W_mulvt + 128 * 256;
    int*   counts   = (int*)(W_dect + 256 * 64);
    int*   offsets  = counts + N_NODES;
    int*   cursor   = offsets + N_NODES + 1;
    int2*  edges    = (int2*)(cursor + N_NODES);
    // align edges to 8B
    edges = (int2*)(((size_t)edges + 7) & ~(size_t)7);
    size_t need = (size_t)((char*)(edges + N_EDGES) - (char*)d_ws);
    if (ws_size < need) return;

    hipMemsetAsync(counts, 0, N_NODES * sizeof(int), stream);
    hipMemsetAsync(cursor, 0, N_NODES * sizeof(int), stream);
    hist_kernel<<<(N_EDGES + 255) / 256, 256, 0, stream>>>(edst, counts);
    scan_kernel<<<1, 1024, 0, stream>>>(counts, offsets);
    scatter_kernel<<<(N_EDGES + 255) / 256, 256, 0, stream>>>(edst, esrc, ew, offsets, cursor,
                                                              edges);

    w1t_kernel<<<(NFEAT * NHID + 255) / 256, 256, 0, stream>>>(W1, W1t);
    w2t_kernel<<<(NCLS_PAD * NFEAT + 255) / 256, 256, 0, stream>>>(W2, W2bt);
    wmlp_kernel<<<(128 * 256 + 256 * 64 + 255) / 256, 256, 0, stream>>>(W_mu, W_lv, W_dec,
                                                                        W_mulvt, W_dect);
    gemm1_mfma<<<(N_NODES + 63) / 64, 256, 0, stream>>>(x, W1t, support1b);
    spmm1_kernel<<<N_NODES / 4, 256, 0, stream>>>(offsets, edges, support1b, b1, x1cat);
    mlp_mfma<<<N_NODES / 16, 256, 0, stream>>>(x1cat, eps, b_mu, b_lv, W_mulvt, b_dec, W_dect,
                                               x1cat);
    gemm2_mfma<<<(N_NODES + 63) / 64, 256, 0, stream>>>(x1cat, W2bt, support2);
    spmm2_softmax_kernel<<<N_NODES / 4, 256, 0, stream>>>(offsets, edges, support2, b2, out);
}

// Round 6
// 556.999 us; speedup vs baseline: 1.4778x; 1.0181x over previous
//
#include <hip/hip_runtime.h>
#include <math.h>

#define N_NODES 50000
#define N_EDGES 800000
#define NFEAT 512
#define NHID 256
#define NCODE 64
#define NCLASS 40
#define NCLS_PAD 48

typedef __attribute__((ext_vector_type(8))) short short8;
typedef __attribute__((ext_vector_type(8))) unsigned short ushort8;
typedef __attribute__((ext_vector_type(4))) unsigned short ushort4v;
typedef __attribute__((ext_vector_type(4))) float floatx4;

__device__ inline unsigned short f2bf(float f) {
    unsigned u = __builtin_bit_cast(unsigned, f);
    u += 0x7fff + ((u >> 16) & 1);
    return (unsigned short)(u >> 16);
}
__device__ inline float bf2f(unsigned short h) {
    return __builtin_bit_cast(float, (unsigned)h << 16);
}

// ---------------- CSR build (by dst) ----------------
__global__ __launch_bounds__(256) void hist_kernel(const int* __restrict__ dst,
                                                   int* __restrict__ counts) {
    int t = blockIdx.x * 256 + threadIdx.x;
    if (t < N_EDGES) atomicAdd(&counts[dst[t]], 1);
}

__global__ __launch_bounds__(1024) void scan_kernel(const int* __restrict__ counts,
                                                    int* __restrict__ offsets) {
    __shared__ int sums[1024];
    int t = threadIdx.x;
    const int CH = (N_NODES + 1023) / 1024;  // 49
    int start = t * CH;
    int end = min(start + CH, N_NODES);
    int s = 0;
    for (int i = start; i < end; i++) s += counts[i];
    sums[t] = s;
    __syncthreads();
    for (int off = 1; off < 1024; off <<= 1) {
        int v = (t >= off) ? sums[t - off] : 0;
        __syncthreads();
        sums[t] += v;
        __syncthreads();
    }
    int run = (t == 0) ? 0 : sums[t - 1];
    for (int i = start; i < end; i++) {
        offsets[i] = run;
        run += counts[i];
    }
    if (t == 1023) offsets[N_NODES] = sums[1023];
}

// scatter edges into dst-sorted order as packed (src, w_bits) int2
__global__ __launch_bounds__(256) void scatter_kernel(const int* __restrict__ dst,
                                                      const int* __restrict__ src,
                                                      const float* __restrict__ w,
                                                      const int* __restrict__ offsets,
                                                      int* __restrict__ cursor,
                                                      int2* __restrict__ edges) {
    int t = blockIdx.x * 256 + threadIdx.x;
    if (t < N_EDGES) {
        int d = dst[t];
        int pos = offsets[d] + atomicAdd(&cursor[d], 1);
        edges[pos] = make_int2(src[t], __builtin_bit_cast(int, w[t]));
    }
}

// ---------------- Fused weight prep: W1t / W2bt / W_mulvt / W_dect ----------------
// W1t[256][512]  = bf16(W1^T)         : 131072
// W2bt[48][512]  = bf16(W2^T, pad 48) : 24576
// W_mulvt[128][256] = bf16([W_mu|W_lv]^T) : 32768
// W_dect[256][64]   = bf16(W_dec^T)   : 16384   -> total 204800 threads
__global__ __launch_bounds__(256) void wprep_kernel(const float* __restrict__ W1,
                                                    const float* __restrict__ W2,
                                                    const float* __restrict__ W_mu,
                                                    const float* __restrict__ W_lv,
                                                    const float* __restrict__ W_dec,
                                                    unsigned short* __restrict__ W1t,
                                                    unsigned short* __restrict__ W2bt,
                                                    unsigned short* __restrict__ W_mulvt,
                                                    unsigned short* __restrict__ W_dect) {
    int idx = blockIdx.x * 256 + threadIdx.x;
    if (idx < NFEAT * NHID) {
        int k = idx >> 8;
        int n = idx & 255;
        W1t[(size_t)n * NFEAT + k] = f2bf(W1[idx]);
    } else if (idx < NFEAT * NHID + NCLS_PAD * NFEAT) {
        int i2 = idx - NFEAT * NHID;
        int n = i2 >> 9;
        int k = i2 & 511;
        W2bt[i2] = (n < NCLASS) ? f2bf(W2[(size_t)k * NCLASS + n]) : (unsigned short)0;
    } else if (idx < NFEAT * NHID + NCLS_PAD * NFEAT + 128 * 256) {
        int i2 = idx - NFEAT * NHID - NCLS_PAD * NFEAT;
        int j = i2 >> 8;
        int k = i2 & 255;
        float v = (j < 64) ? W_mu[(size_t)k * NCODE + j] : W_lv[(size_t)k * NCODE + (j - 64)];
        W_mulvt[i2] = f2bf(v);
    } else if (idx < NFEAT * NHID + NCLS_PAD * NFEAT + 128 * 256 + 256 * 64) {
        int i2 = idx - NFEAT * NHID - NCLS_PAD * NFEAT - 128 * 256;
        int n = i2 >> 6;
        int k = i2 & 63;
        W_dect[i2] = f2bf(W_dec[(size_t)k * NHID + n]);
    }
}

// ---------------- GEMM1 (bf16 MFMA, reg-prefetch pipelined): support1b = bf16(x @ W1) --------
__global__ __launch_bounds__(256) void gemm1_mfma(const float* __restrict__ A,
                                                  const unsigned short* __restrict__ Bt,
                                                  unsigned short* __restrict__ C) {
    __shared__ unsigned short As[64][40];
    __shared__ unsigned short Bs[256][40];
    int t = threadIdx.x;
    int wave = t >> 6, lane = t & 63;
    int quad = lane >> 4, m16 = lane & 15;
    int m0 = blockIdx.x * 64;

    floatx4 acc[16];
#pragma unroll
    for (int i = 0; i < 16; i++) acc[i] = (floatx4){0.f, 0.f, 0.f, 0.f};

    int ar = t >> 2;
    int ako = (t & 3) * 8;
    int arow = m0 + ar;
    if (arow >= N_NODES) arow = N_NODES - 1;
    const float* Abase = A + (size_t)arow * NFEAT + ako;
    const unsigned short* Bbase = Bt + (size_t)t * NFEAT;

    // prologue: load k-chunk 0 into registers
    float4 a0 = *(const float4*)(Abase);
    float4 a1 = *(const float4*)(Abase + 4);
    ushort8 b0 = *(const ushort8*)(Bbase);
    ushort8 b1 = *(const ushort8*)(Bbase + 8);
    ushort8 b2 = *(const ushort8*)(Bbase + 16);
    ushort8 b3 = *(const ushort8*)(Bbase + 24);

    for (int k0 = 0; k0 < NFEAT; k0 += 32) {
        __syncthreads();  // prior LDS reads done
        ushort8 av;
        av[0] = f2bf(a0.x); av[1] = f2bf(a0.y); av[2] = f2bf(a0.z); av[3] = f2bf(a0.w);
        av[4] = f2bf(a1.x); av[5] = f2bf(a1.y); av[6] = f2bf(a1.z); av[7] = f2bf(a1.w);
        *(ushort8*)&As[ar][ako] = av;
        *(ushort8*)&Bs[t][0]  = b0;
        *(ushort8*)&Bs[t][8]  = b1;
        *(ushort8*)&Bs[t][16] = b2;
        *(ushort8*)&Bs[t][24] = b3;
        __syncthreads();
        // prefetch next chunk: issued before MFMA so vmcnt drain overlaps compute
        int kn = (k0 + 32 < NFEAT) ? (k0 + 32) : k0;
        a0 = *(const float4*)(Abase + kn);
        a1 = *(const float4*)(Abase + kn + 4);
        b0 = *(const ushort8*)(Bbase + kn);
        b1 = *(const ushort8*)(Bbase + kn + 8);
        b2 = *(const ushort8*)(Bbase + kn + 16);
        b3 = *(const ushort8*)(Bbase + kn + 24);
        short8 afrag = *(const short8*)&As[wave * 16 + m16][quad * 8];
#pragma unroll
        for (int nt = 0; nt < 16; nt++) {
            short8 bfrag = *(const short8*)&Bs[nt * 16 + m16][quad * 8];
            acc[nt] = __builtin_amdgcn_mfma_f32_16x16x32_bf16(afrag, bfrag, acc[nt], 0, 0, 0);
        }
    }
#pragma unroll
    for (int nt = 0; nt < 16; nt++) {
        int col = nt * 16 + m16;
#pragma unroll
        for (int r = 0; r < 4; r++) {
            int row = m0 + wave * 16 + quad * 4 + r;
            if (row < N_NODES) C[(size_t)row * NHID + col] = f2bf(acc[nt][r]);
        }
    }
}

// ---------------- SpMM1 + bias + relu -> x1cat[:,256:512] (bf16) ----------------
__global__ __launch_bounds__(256) void spmm1_kernel(const int* __restrict__ offsets,
                                                    const int2* __restrict__ edges,
                                                    const unsigned short* __restrict__ S1b,
                                                    const float* __restrict__ b1,
                                                    unsigned short* __restrict__ x1cat) {
    int n = blockIdx.x * 4 + (threadIdx.x >> 6);
    int lane = threadIdx.x & 63;
    int beg = offsets[n], end = offsets[n + 1];
    float ax = 0.f, ay = 0.f, az = 0.f, aw = 0.f;
    int i = beg;
    for (; i + 4 <= end; i += 4) {
        int2 e0 = edges[i], e1 = edges[i + 1], e2 = edges[i + 2], e3 = edges[i + 3];
        float w0 = __builtin_bit_cast(float, e0.y);
        float w1 = __builtin_bit_cast(float, e1.y);
        float w2 = __builtin_bit_cast(float, e2.y);
        float w3 = __builtin_bit_cast(float, e3.y);
        ushort4v r0 = *(const ushort4v*)&S1b[(size_t)e0.x * NHID + lane * 4];
        ushort4v r1 = *(const ushort4v*)&S1b[(size_t)e1.x * NHID + lane * 4];
        ushort4v r2 = *(const ushort4v*)&S1b[(size_t)e2.x * NHID + lane * 4];
        ushort4v r3 = *(const ushort4v*)&S1b[(size_t)e3.x * NHID + lane * 4];
        ax += w0 * bf2f(r0[0]) + w1 * bf2f(r1[0]) + w2 * bf2f(r2[0]) + w3 * bf2f(r3[0]);
        ay += w0 * bf2f(r0[1]) + w1 * bf2f(r1[1]) + w2 * bf2f(r2[1]) + w3 * bf2f(r3[1]);
        az += w0 * bf2f(r0[2]) + w1 * bf2f(r1[2]) + w2 * bf2f(r2[2]) + w3 * bf2f(r3[2]);
        aw += w0 * bf2f(r0[3]) + w1 * bf2f(r1[3]) + w2 * bf2f(r2[3]) + w3 * bf2f(r3[3]);
    }
    for (; i < end; i++) {
        int2 e = edges[i];
        float ww = __builtin_bit_cast(float, e.y);
        ushort4v r = *(const ushort4v*)&S1b[(size_t)e.x * NHID + lane * 4];
        ax += ww * bf2f(r[0]); ay += ww * bf2f(r[1]);
        az += ww * bf2f(r[2]); aw += ww * bf2f(r[3]);
    }
    float4 bb = *(const float4*)&b1[lane * 4];
    ushort4v hb;
    hb[0] = f2bf(fmaxf(ax + bb.x, 0.f));
    hb[1] = f2bf(fmaxf(ay + bb.y, 0.f));
    hb[2] = f2bf(fmaxf(az + bb.z, 0.f));
    hb[3] = f2bf(fmaxf(aw + bb.w, 0.f));
    *(ushort4v*)&x1cat[(size_t)n * (2 * NHID) + NHID + lane * 4] = hb;
}

// ---------------- Fused MLP via MFMA: 16 nodes/block ----------------
__global__ __launch_bounds__(256) void mlp_mfma(const unsigned short* __restrict__ x1cat_ro,
                                                const float* __restrict__ eps,
                                                const float* __restrict__ b_mu,
                                                const float* __restrict__ b_lv,
                                                const unsigned short* __restrict__ W_mulvt,
                                                const float* __restrict__ b_dec,
                                                const unsigned short* __restrict__ W_dect,
                                                unsigned short* __restrict__ x1cat) {
    __shared__ float smulv[16][132];
    __shared__ unsigned short z_bf[16][72];
    int t = threadIdx.x;
    int wave = t >> 6, lane = t & 63;
    int quad = lane >> 4, m16 = lane & 15;
    int node0 = blockIdx.x * 16;

    // ---- phase A: mu||lv = h1 @ W_mulvt ----
    {
        floatx4 acc[2];
        acc[0] = (floatx4){0.f, 0.f, 0.f, 0.f};
        acc[1] = (floatx4){0.f, 0.f, 0.f, 0.f};
        const unsigned short* Abase =
            x1cat_ro + (size_t)(node0 + m16) * 512 + 256 + quad * 8;
        const unsigned short* Bb0 = W_mulvt + (size_t)(wave * 32 + m16) * 256 + quad * 8;
        const unsigned short* Bb1 = Bb0 + 16 * 256;
#pragma unroll
        for (int k0 = 0; k0 < 256; k0 += 32) {
            short8 afrag = *(const short8*)(Abase + k0);
            short8 bf0 = *(const short8*)(Bb0 + k0);
            short8 bf1 = *(const short8*)(Bb1 + k0);
            acc[0] = __builtin_amdgcn_mfma_f32_16x16x32_bf16(afrag, bf0, acc[0], 0, 0, 0);
            acc[1] = __builtin_amdgcn_mfma_f32_16x16x32_bf16(afrag, bf1, acc[1], 0, 0, 0);
        }
#pragma unroll
        for (int nt = 0; nt < 2; nt++) {
            int j = wave * 32 + nt * 16 + m16;
            float bias = (j < 64) ? b_mu[j] : b_lv[j - 64];
#pragma unroll
            for (int r = 0; r < 4; r++)
                smulv[quad * 4 + r][j] = acc[nt][r] + bias;
        }
    }
    __syncthreads();
    // ---- phase B: z = mu + eps*exp(lv) ----
#pragma unroll
    for (int r = 0; r < 4; r++) {
        int idx = t + r * 256;
        int n = idx >> 6, j = idx & 63;
        float z = smulv[n][j] + eps[(size_t)node0 * NCODE + idx] * expf(smulv[n][64 + j]);
        z_bf[n][j] = f2bf(z);
    }
    __syncthreads();
    // ---- phase C: x1 = relu(z @ W_dect + b_dec) ----
    {
        floatx4 acc[4];
#pragma unroll
        for (int i = 0; i < 4; i++) acc[i] = (floatx4){0.f, 0.f, 0.f, 0.f};
#pragma unroll
        for (int ks = 0; ks < 2; ks++) {
            int k0 = ks * 32;
            short8 afrag = *(const short8*)&z_bf[m16][k0 + quad * 8];
#pragma unroll
            for (int nt = 0; nt < 4; nt++) {
                int col = wave * 64 + nt * 16 + m16;
                short8 bfrag = *(const short8*)(W_dect + (size_t)col * 64 + k0 + quad * 8);
                acc[nt] = __builtin_amdgcn_mfma_f32_16x16x32_bf16(afrag, bfrag, acc[nt], 0, 0, 0);
            }
        }
#pragma unroll
        for (int nt = 0; nt < 4; nt++) {
            int col = wave * 64 + nt * 16 + m16;
            float bias = b_dec[col];
#pragma unroll
            for (int r = 0; r < 4; r++) {
                int node = node0 + quad * 4 + r;
                x1cat[(size_t)node * 512 + col] = f2bf(fmaxf(acc[nt][r] + bias, 0.f));
            }
        }
    }
}

// ---------------- GEMM2 (bf16 MFMA, reg-prefetch pipelined): support2 = x1cat @ W2 ------------
__global__ __launch_bounds__(256) void gemm2_mfma(const unsigned short* __restrict__ Xb,
                                                  const unsigned short* __restrict__ Bt,
                                                  float* __restrict__ S2) {
    __shared__ unsigned short As[64][40];
    __shared__ unsigned short Bs[48][40];
    int t = threadIdx.x;
    int wave = t >> 6, lane = t & 63;
    int quad = lane >> 4, m16 = lane & 15;
    int m0 = blockIdx.x * 64;

    floatx4 acc[3];
#pragma unroll
    for (int i = 0; i < 3; i++) acc[i] = (floatx4){0.f, 0.f, 0.f, 0.f};

    int ar = t >> 2;
    int ako = (t & 3) * 8;
    int arow = m0 + ar;
    if (arow >= N_NODES) arow = N_NODES - 1;
    const unsigned short* Abase = Xb + (size_t)arow * NFEAT + ako;
    const unsigned short* Bbase = Bt + (size_t)(t >> 2) * NFEAT + ako;
    bool bload = (t >> 2) < NCLS_PAD;

    ushort8 a0 = *(const ushort8*)(Abase);
    ushort8 b0;
    if (bload) b0 = *(const ushort8*)(Bbase);

    for (int k0 = 0; k0 < NFEAT; k0 += 32) {
        __syncthreads();
        *(ushort8*)&As[ar][ako] = a0;
        if (bload) *(ushort8*)&Bs[t >> 2][ako] = b0;
        __syncthreads();
        int kn = (k0 + 32 < NFEAT) ? (k0 + 32) : k0;
        a0 = *(const ushort8*)(Abase + kn);
        if (bload) b0 = *(const ushort8*)(Bbase + kn);
        short8 afrag = *(const short8*)&As[wave * 16 + m16][quad * 8];
#pragma unroll
        for (int nt = 0; nt < 3; nt++) {
            short8 bfrag = *(const short8*)&Bs[nt * 16 + m16][quad * 8];
            acc[nt] = __builtin_amdgcn_mfma_f32_16x16x32_bf16(afrag, bfrag, acc[nt], 0, 0, 0);
        }
    }
#pragma unroll
    for (int nt = 0; nt < 3; nt++) {
        int col = nt * 16 + m16;
        if (col < NCLASS) {
#pragma unroll
            for (int r = 0; r < 4; r++) {
                int row = m0 + wave * 16 + quad * 4 + r;
                if (row < N_NODES) S2[(size_t)row * NCLASS + col] = acc[nt][r];
            }
        }
    }
}

// ---------------- SpMM2 + bias + log_softmax -> out ----------------
__global__ __launch_bounds__(256) void spmm2_softmax_kernel(const int* __restrict__ offsets,
                                                            const int2* __restrict__ edges,
                                                            const float* __restrict__ S2,
                                                            const float* __restrict__ b2,
                                                            float* __restrict__ out) {
    int wave = threadIdx.x >> 6;
    int lane = threadIdx.x & 63;
    int n = blockIdx.x * 4 + wave;
    int beg = offsets[n], end = offsets[n + 1];
    float acc = 0.f;
    int i = beg;
    for (; i + 2 <= end; i += 2) {
        int2 e0 = edges[i], e1 = edges[i + 1];
        float w0 = __builtin_bit_cast(float, e0.y);
        float w1 = __builtin_bit_cast(float, e1.y);
        if (lane < NCLASS) {
            float v0 = S2[(size_t)e0.x * NCLASS + lane];
            float v1 = S2[(size_t)e1.x * NCLASS + lane];
            acc += w0 * v0 + w1 * v1;
        }
    }
    for (; i < end; i++) {
        int2 e = edges[i];
        float ww = __builtin_bit_cast(float, e.y);
        if (lane < NCLASS) acc += ww * S2[(size_t)e.x * NCLASS + lane];
    }
    float v = (lane < NCLASS) ? (acc + b2[lane]) : -INFINITY;
    float m = v;
#pragma unroll
    for (int off = 32; off > 0; off >>= 1) m = fmaxf(m, __shfl_xor(m, off));
    float ex = (lane < NCLASS) ? expf(v - m) : 0.f;
    float ssum = ex;
#pragma unroll
    for (int off = 32; off > 0; off >>= 1) ssum += __shfl_xor(ssum, off);
    if (lane < NCLASS) out[(size_t)n * NCLASS + lane] = v - m - logf(ssum);
}

extern "C" void kernel_launch(void* const* d_in, const int* in_sizes, int n_in,
                              void* d_out, int out_size, void* d_ws, size_t ws_size,
                              hipStream_t stream) {
    const float* x     = (const float*)d_in[0];
    const int*   esrc  = (const int*)d_in[1];
    const int*   edst  = (const int*)d_in[2];
    const float* ew    = (const float*)d_in[3];
    const float* eps   = (const float*)d_in[4];
    const float* W1    = (const float*)d_in[5];
    const float* b1    = (const float*)d_in[6];
    const float* W_mu  = (const float*)d_in[7];
    const float* b_mu  = (const float*)d_in[8];
    const float* W_lv  = (const float*)d_in[9];
    const float* b_lv  = (const float*)d_in[10];
    const float* W_dec = (const float*)d_in[11];
    const float* b_dec = (const float*)d_in[12];
    const float* W2    = (const float*)d_in[13];
    const float* b2    = (const float*)d_in[14];
    float* out = (float*)d_out;

    // workspace layout (counts & cursor adjacent -> single memset)
    unsigned short* support1b = (unsigned short*)d_ws;                     // 12.8M u16
    unsigned short* x1cat = support1b + (size_t)N_NODES * NHID;            // 25.6M u16
    float* support2 = (float*)(x1cat + (size_t)N_NODES * 2 * NHID);        // 2M f32
    unsigned short* W1t    = (unsigned short*)(support2 + (size_t)N_NODES * NCLASS);
    unsigned short* W2bt   = W1t + (size_t)NHID * NFEAT;
    unsigned short* W_mulvt = W2bt + (size_t)NCLS_PAD * NFEAT;
    unsigned short* W_dect  = W_mulvt + 128 * 256;
    int*   counts   = (int*)(W_dect + 256 * 64);
    int*   cursor   = counts + N_NODES;
    int*   offsets  = cursor + N_NODES;     // N+1
    int2*  edges    = (int2*)(offsets + N_NODES + 1);
    edges = (int2*)(((size_t)edges + 7) & ~(size_t)7);
    size_t need = (size_t)((char*)(edges + N_EDGES) - (char*)d_ws);
    if (ws_size < need) return;

    hipMemsetAsync(counts, 0, 2 * N_NODES * sizeof(int), stream);  // counts + cursor
    hist_kernel<<<(N_EDGES + 255) / 256, 256, 0, stream>>>(edst, counts);
    scan_kernel<<<1, 1024, 0, stream>>>(counts, offsets);
    scatter_kernel<<<(N_EDGES + 255) / 256, 256, 0, stream>>>(edst, esrc, ew, offsets, cursor,
                                                              edges);

    wprep_kernel<<<800, 256, 0, stream>>>(W1, W2, W_mu, W_lv, W_dec, W1t, W2bt, W_mulvt, W_dect);
    gemm1_mfma<<<(N_NODES + 63) / 64, 256, 0, stream>>>(x, W1t, support1b);
    spmm1_kernel<<<N_NODES / 4, 256, 0, stream>>>(offsets, edges, support1b, b1, x1cat);
    mlp_mfma<<<N_NODES / 16, 256, 0, stream>>>(x1cat, eps, b_mu, b_lv, W_mulvt, b_dec, W_dect,
                                               x1cat);
    gemm2_mfma<<<(N_NODES + 63) / 64, 256, 0, stream>>>(x1cat, W2bt, support2);
    spmm2_softmax_kernel<<<N_NODES / 4, 256, 0, stream>>>(offsets, edges, support2, b2, out);
}